// Round 4
// baseline (50.659 us; speedup 1.0000x reference)
//
#include <hip/hip_runtime.h>
#include <math.h>

#define HW 4096
#define NCH 4
#define TPB 512                               // 8 waves/block
#define WAVES (TPB / 64)
#define R 2                                   // rows per wave
#define ROWS_PER_BLOCK (WAVES * R)            // 16
#define BLOCKS_PER_CH (HW / ROWS_PER_BLOCK)   // 256
#define NBLOCKS (NCH * BLOCKS_PER_CH)         // 1024
#define KNN 5

// digamma for x >= 6 here (counts always >= k+1 = 6).
// Shift-up recurrence kept for safety; asymptotic series. ~1e-7 abs error.
__device__ __forceinline__ float digammaf_dev(float x) {
    float r = 0.f;
    while (x < 6.f) { r -= 1.f / x; x += 1.f; }
    float f = 1.f / x, f2 = f * f;
    return logf(x) - 0.5f * f
         - f2 * (1.f / 12.f - f2 * (1.f / 120.f - f2 * (1.f / 252.f))) + r;
}

// Insert d into ascending sorted 6-list (drop the max).
// s0' = min(s0,d); si' = med3(s[i-1], s[i], d) -- 6 independent v_med3_f32.
__device__ __forceinline__ void insert6(float (&s)[6], float d) {
    float n0 = fminf(s[0], d);
    float n1 = __builtin_amdgcn_fmed3f(s[0], s[1], d);
    float n2 = __builtin_amdgcn_fmed3f(s[1], s[2], d);
    float n3 = __builtin_amdgcn_fmed3f(s[2], s[3], d);
    float n4 = __builtin_amdgcn_fmed3f(s[3], s[4], d);
    float n5 = __builtin_amdgcn_fmed3f(s[4], s[5], d);
    s[0] = n0; s[1] = n1; s[2] = n2; s[3] = n3; s[4] = n4; s[5] = n5;
}

__global__ __launch_bounds__(TPB, 8) void knnmi_rows(const float* __restrict__ x,
                                                     const float* __restrict__ y,
                                                     float* __restrict__ ws) {
    __shared__ float2 sxy[HW];                 // exactly 32 KB

    const int c  = blockIdx.x / BLOCKS_PER_CH;   // channel 0..3
    const int rb = blockIdx.x % BLOCKS_PER_CH;   // row-block within channel

    const float* xc = x + c * HW;
    const float* yc = y + c * HW;

    // Stage interleaved {x,y} via float4 loads + b128 LDS writes (2 iters).
    for (int i = threadIdx.x; i < HW / 4; i += TPB) {
        float4 xv = ((const float4*)xc)[i];
        float4 yv = ((const float4*)yc)[i];
        ((float4*)sxy)[2 * i]     = make_float4(xv.x, yv.x, xv.y, yv.y);
        ((float4*)sxy)[2 * i + 1] = make_float4(xv.z, yv.z, xv.w, yv.w);
    }
    __syncthreads();

    const int wv    = threadIdx.x >> 6;          // wave 0..7
    const int lane  = threadIdx.x & 63;
    const int rbase = rb * ROWS_PER_BLOCK + wv * R;   // wave owns 2 rows

    float xr[R], yr[R];
#pragma unroll
    for (int r = 0; r < R; ++r) {
        float2 p = sxy[rbase + r];               // uniform addr -> broadcast
        xr[r] = p.x; yr[r] = p.y;
    }

    // Pass 1: lane scans candidates j = it*64 + lane; one ds_read_b64
    // serves both rows.
    float s[R][6];
#pragma unroll
    for (int r = 0; r < R; ++r)
#pragma unroll
        for (int q = 0; q < 6; ++q) s[r][q] = 3.4e38f;

#pragma unroll 16
    for (int it = 0; it < HW / 64; ++it) {
        float2 p = sxy[it * 64 + lane];
#pragma unroll
        for (int r = 0; r < R; ++r) {
            float d = fmaxf(fabsf(xr[r] - p.x), fabsf(yr[r] - p.y));
            insert6(s[r], d);
        }
    }

    // Butterfly merge of 64 per-lane sorted 6-lists (per row).
#pragma unroll
    for (int m = 1; m < 64; m <<= 1) {
#pragma unroll
        for (int r = 0; r < R; ++r) {
            float o[6];
#pragma unroll
            for (int q = 0; q < 6; ++q) o[q] = __shfl_xor(s[r][q], m);
#pragma unroll
            for (int q = 0; q < 6; ++q) insert6(s[r], o[q]);
        }
    }

    float eps[R];
#pragma unroll
    for (int r = 0; r < R; ++r) eps[r] = s[r][5];  // (k+1)-th smallest, k=5

    // Pass 2: strict-< marginal counts (self included, as in ref).
    int nx[R] = {0, 0}, ny[R] = {0, 0};
#pragma unroll 16
    for (int it = 0; it < HW / 64; ++it) {
        float2 p = sxy[it * 64 + lane];
#pragma unroll
        for (int r = 0; r < R; ++r) {
            nx[r] += (fabsf(xr[r] - p.x) < eps[r]);
            ny[r] += (fabsf(yr[r] - p.y) < eps[r]);
        }
    }

    // Cross-lane count reduce: per-lane counts <= 64, totals <= 4096.
    int pk[R];
#pragma unroll
    for (int r = 0; r < R; ++r) pk[r] = (nx[r] << 16) | ny[r];
#pragma unroll
    for (int m = 1; m < 64; m <<= 1)
#pragma unroll
        for (int r = 0; r < R; ++r) pk[r] += __shfl_xor(pk[r], m);

    if (lane == 0) {
        float v = 0.f;
#pragma unroll
        for (int r = 0; r < R; ++r)
            v += digammaf_dev((float)(pk[r] >> 16))
               + digammaf_dev((float)(pk[r] & 0xffff));
        ws[blockIdx.x * WAVES + wv] = v;         // per-wave partial
    }
}

__global__ void knnmi_final(const float* __restrict__ ws, float* __restrict__ out) {
    const int w    = threadIdx.x >> 6;    // wave = channel
    const int lane = threadIdx.x & 63;
    const int n    = BLOCKS_PER_CH * WAVES;   // 2048 partials per channel
    float sum = 0.f;
    for (int i = lane; i < n; i += 64) sum += ws[w * n + i];
#pragma unroll
    for (int m = 32; m; m >>= 1) sum += __shfl_xor(sum, m);
    if (lane == 0) {
        float mi = digammaf_dev((float)KNN) + digammaf_dev((float)HW)
                 - sum / (float)HW;
        out[w] = fmaxf(mi, 0.f);
    }
}

extern "C" void kernel_launch(void* const* d_in, const int* in_sizes, int n_in,
                              void* d_out, int out_size, void* d_ws, size_t ws_size,
                              hipStream_t stream) {
    const float* x = (const float*)d_in[0];
    const float* y = (const float*)d_in[1];
    float* out = (float*)d_out;
    float* ws  = (float*)d_ws;   // NBLOCKS*WAVES floats, fully rewritten every call

    knnmi_rows<<<NBLOCKS, TPB, 0, stream>>>(x, y, ws);
    knnmi_final<<<1, NCH * 64, 0, stream>>>(ws, out);
}

// Round 5
// 50.162 us; speedup vs baseline: 1.0099x; 1.0099x over previous
//
#include <hip/hip_runtime.h>
#include <math.h>

#define HW 4096
#define NCH 4
#define TPB 512                               // 8 waves/block
#define WAVES (TPB / 64)
#define R 2                                   // rows per wave
#define ROWS_PER_BLOCK (WAVES * R)            // 16
#define BLOCKS_PER_CH (HW / ROWS_PER_BLOCK)   // 256
#define NBLOCKS (NCH * BLOCKS_PER_CH)         // 1024
#define KNN 5

// digamma for positive integer args (here always >= 6).
// Shift-up recurrence kept for safety; asymptotic series. ~1e-7 abs error.
__device__ __forceinline__ float digammaf_dev(float x) {
    float r = 0.f;
    while (x < 6.f) { r -= 1.f / x; x += 1.f; }
    float f = 1.f / x, f2 = f * f;
    return logf(x) - 0.5f * f
         - f2 * (1.f / 12.f - f2 * (1.f / 120.f - f2 * (1.f / 252.f))) + r;
}

// Insert d into ascending sorted 6-list (drop the max).
// s0' = min(s0,d); si' = med3(s[i-1], s[i], d) -- 6 independent v_med3_f32.
__device__ __forceinline__ void insert6(float (&s)[6], float d) {
    float n0 = fminf(s[0], d);
    float n1 = __builtin_amdgcn_fmed3f(s[0], s[1], d);
    float n2 = __builtin_amdgcn_fmed3f(s[1], s[2], d);
    float n3 = __builtin_amdgcn_fmed3f(s[2], s[3], d);
    float n4 = __builtin_amdgcn_fmed3f(s[3], s[4], d);
    float n5 = __builtin_amdgcn_fmed3f(s[4], s[5], d);
    s[0] = n0; s[1] = n1; s[2] = n2; s[3] = n3; s[4] = n4; s[5] = n5;
}

__global__ __launch_bounds__(TPB, 4) void knnmi_rows(const float* __restrict__ x,
                                                     const float* __restrict__ y,
                                                     float* __restrict__ ws) {
    __shared__ float2 sxy[HW];                 // exactly 32 KB

    const int c  = blockIdx.x / BLOCKS_PER_CH;   // channel 0..3
    const int rb = blockIdx.x % BLOCKS_PER_CH;   // row-block within channel

    const float* xc = x + c * HW;
    const float* yc = y + c * HW;

    // Stage interleaved {x,y} via float4 loads + b128 LDS writes (2 iters).
    for (int i = threadIdx.x; i < HW / 4; i += TPB) {
        float4 xv = ((const float4*)xc)[i];
        float4 yv = ((const float4*)yc)[i];
        ((float4*)sxy)[2 * i]     = make_float4(xv.x, yv.x, xv.y, yv.y);
        ((float4*)sxy)[2 * i + 1] = make_float4(xv.z, yv.z, xv.w, yv.w);
    }
    __syncthreads();

    const int wv    = threadIdx.x >> 6;          // wave 0..7
    const int lane  = threadIdx.x & 63;
    const int rbase = rb * ROWS_PER_BLOCK + wv * R;   // wave owns 2 rows

    float xr[R], yr[R];
#pragma unroll
    for (int r = 0; r < R; ++r) {
        float2 p = sxy[rbase + r];               // uniform addr -> broadcast
        xr[r] = p.x; yr[r] = p.y;
    }

    // Pass 1: each lane reads 2 candidate points per ds_read_b128:
    // j0 = it*128 + 2*lane, j1 = j0+1. One read serves both rows and
    // yields two independent insert chains per row.
    float s[R][6];
#pragma unroll
    for (int r = 0; r < R; ++r)
#pragma unroll
        for (int q = 0; q < 6; ++q) s[r][q] = 3.4e38f;

#pragma unroll 4
    for (int it = 0; it < HW / 128; ++it) {
        float4 p = ((const float4*)sxy)[it * 64 + lane];   // {x0,y0,x1,y1}
#pragma unroll
        for (int r = 0; r < R; ++r) {
            float d0 = fmaxf(fabsf(xr[r] - p.x), fabsf(yr[r] - p.y));
            float d1 = fmaxf(fabsf(xr[r] - p.z), fabsf(yr[r] - p.w));
            insert6(s[r], d0);
            insert6(s[r], d1);
        }
    }

    // Butterfly merge of 64 per-lane sorted 6-lists (per row).
#pragma unroll
    for (int m = 1; m < 64; m <<= 1) {
#pragma unroll
        for (int r = 0; r < R; ++r) {
            float o[6];
#pragma unroll
            for (int q = 0; q < 6; ++q) o[q] = __shfl_xor(s[r][q], m);
#pragma unroll
            for (int q = 0; q < 6; ++q) insert6(s[r], o[q]);
        }
    }

    float eps[R];
#pragma unroll
    for (int r = 0; r < R; ++r) eps[r] = s[r][5];  // (k+1)-th smallest, k=5

    // Pass 2: strict-< marginal counts (self included, as in ref).
    int nx[R] = {0, 0}, ny[R] = {0, 0};
#pragma unroll 4
    for (int it = 0; it < HW / 128; ++it) {
        float4 p = ((const float4*)sxy)[it * 64 + lane];
#pragma unroll
        for (int r = 0; r < R; ++r) {
            nx[r] += (fabsf(xr[r] - p.x) < eps[r]);
            ny[r] += (fabsf(yr[r] - p.y) < eps[r]);
            nx[r] += (fabsf(xr[r] - p.z) < eps[r]);
            ny[r] += (fabsf(yr[r] - p.w) < eps[r]);
        }
    }

    // Cross-lane count reduce: per-lane counts <= 128, totals <= 4096.
    int pk[R];
#pragma unroll
    for (int r = 0; r < R; ++r) pk[r] = (nx[r] << 16) | ny[r];
#pragma unroll
    for (int m = 1; m < 64; m <<= 1)
#pragma unroll
        for (int r = 0; r < R; ++r) pk[r] += __shfl_xor(pk[r], m);

    if (lane == 0) {
        float v = 0.f;
#pragma unroll
        for (int r = 0; r < R; ++r)
            v += digammaf_dev((float)(pk[r] >> 16))
               + digammaf_dev((float)(pk[r] & 0xffff));
        ws[blockIdx.x * WAVES + wv] = v;         // per-wave partial
    }
}

__global__ void knnmi_final(const float* __restrict__ ws, float* __restrict__ out) {
    const int w    = threadIdx.x >> 6;    // wave = channel
    const int lane = threadIdx.x & 63;
    const int n    = BLOCKS_PER_CH * WAVES;   // 2048 partials per channel
    float sum = 0.f;
    for (int i = lane; i < n; i += 64) sum += ws[w * n + i];
#pragma unroll
    for (int m = 32; m; m >>= 1) sum += __shfl_xor(sum, m);
    if (lane == 0) {
        float mi = digammaf_dev((float)KNN) + digammaf_dev((float)HW)
                 - sum / (float)HW;
        out[w] = fmaxf(mi, 0.f);
    }
}

extern "C" void kernel_launch(void* const* d_in, const int* in_sizes, int n_in,
                              void* d_out, int out_size, void* d_ws, size_t ws_size,
                              hipStream_t stream) {
    const float* x = (const float*)d_in[0];
    const float* y = (const float*)d_in[1];
    float* out = (float*)d_out;
    float* ws  = (float*)d_ws;   // NBLOCKS*WAVES floats, fully rewritten every call

    knnmi_rows<<<NBLOCKS, TPB, 0, stream>>>(x, y, ws);
    knnmi_final<<<1, NCH * 64, 0, stream>>>(ws, out);
}

// Round 6
// 35.295 us; speedup vs baseline: 1.4353x; 1.4213x over previous
//
#include <hip/hip_runtime.h>
#include <math.h>

#define HW 4096
#define NCH 4
#define TPB 256                               // 4 waves/block
#define G 16                                  // lanes per row (group)
#define ROWS_PER_BLOCK 16                     // 4 waves x 4 rows/wave
#define BLOCKS_PER_CH (HW / ROWS_PER_BLOCK)   // 256
#define NBLOCKS (NCH * BLOCKS_PER_CH)         // 1024
#define KNN 5

// digamma for positive integer args (here always >= 5).
// Shift-up recurrence to x >= 6, then asymptotic series. ~1e-7 abs error.
__device__ __forceinline__ float digammaf_dev(float x) {
    float r = 0.f;
    while (x < 6.f) { r -= 1.f / x; x += 1.f; }
    float f = 1.f / x, f2 = f * f;
    return logf(x) - 0.5f * f
         - f2 * (1.f / 12.f - f2 * (1.f / 120.f - f2 * (1.f / 252.f))) + r;
}

// Insert d into ascending sorted 6-list (drop the max).
// s0' = min(s0,d); si' = med3(s[i-1], s[i], d) -- 6 independent v_med3_f32.
__device__ __forceinline__ void insert6(float (&s)[6], float d) {
    float n0 = fminf(s[0], d);
    float n1 = __builtin_amdgcn_fmed3f(s[0], s[1], d);
    float n2 = __builtin_amdgcn_fmed3f(s[1], s[2], d);
    float n3 = __builtin_amdgcn_fmed3f(s[2], s[3], d);
    float n4 = __builtin_amdgcn_fmed3f(s[3], s[4], d);
    float n5 = __builtin_amdgcn_fmed3f(s[4], s[5], d);
    s[0] = n0; s[1] = n1; s[2] = n2; s[3] = n3; s[4] = n4; s[5] = n5;
}

__global__ __launch_bounds__(TPB) void knnmi_rows(const float* __restrict__ x,
                                                  const float* __restrict__ y,
                                                  float* __restrict__ ws) {
    __shared__ float2 sxy[HW];                 // 32 KB interleaved {x,y}
    __shared__ float red[ROWS_PER_BLOCK];

    const int c  = blockIdx.x >> 8;            // channel 0..3
    const int rb = blockIdx.x & 255;           // row-block within channel

    const float* xc = x + c * HW;
    const float* yc = y + c * HW;

    // Stage interleaved {x,y} via float4 loads + b128 LDS writes (4 iters).
    for (int i = threadIdx.x; i < HW / 4; i += TPB) {
        float4 xv = ((const float4*)xc)[i];
        float4 yv = ((const float4*)yc)[i];
        ((float4*)sxy)[2 * i]     = make_float4(xv.x, yv.x, xv.y, yv.y);
        ((float4*)sxy)[2 * i + 1] = make_float4(xv.z, yv.z, xv.w, yv.w);
    }
    __syncthreads();

    const int wv   = threadIdx.x >> 6;         // wave 0..3
    const int lane = threadIdx.x & 63;
    const int l    = lane & (G - 1);           // lane within 16-lane group
    const int g    = lane >> 4;                // group = row within wave
    const int row  = rb * ROWS_PER_BLOCK + wv * 4 + g;

    const float2 pr = sxy[row];                // broadcast (4 distinct addrs)
    const float xi = pr.x, yi = pr.y;

    const float4* f4 = (const float4*)sxy;     // entry f = pairs (2f, 2f+1)

    // Pass 1: lane reads 2 candidate pairs per ds_read_b128 at f = it*16+l.
    // All 4 groups read the SAME 16 addresses -> LDS broadcast, 256 B/op.
    float s[6];
#pragma unroll
    for (int q = 0; q < 6; ++q) s[q] = 3.4e38f;

#pragma unroll 8
    for (int it = 0; it < HW / (2 * G); ++it) {      // 128 iters
        float4 p = f4[it * G + l];                   // {x0,y0,x1,y1}
        float d0 = fmaxf(fabsf(xi - p.x), fabsf(yi - p.y));
        float d1 = fmaxf(fabsf(xi - p.z), fabsf(yi - p.w));
        insert6(s, d0);
        insert6(s, d1);
    }

    // Merge 16 per-lane sorted 6-lists within each group; the 4 groups
    // merge in parallel inside the same wave-wide shuffle ops (4 stages).
#pragma unroll
    for (int m = 1; m < G; m <<= 1) {
        float o[6];
#pragma unroll
        for (int q = 0; q < 6; ++q) o[q] = __shfl_xor(s[q], m);
#pragma unroll
        for (int q = 0; q < 6; ++q) insert6(s, o[q]);
    }
    const float eps = s[5];   // (k+1)-th smallest joint distance, self incl.

    // Pass 2: strict-< marginal counts (self included, as in ref).
    int nx = 0, ny = 0;
#pragma unroll 8
    for (int it = 0; it < HW / (2 * G); ++it) {
        float4 p = f4[it * G + l];
        nx += (fabsf(xi - p.x) < eps);
        ny += (fabsf(yi - p.y) < eps);
        nx += (fabsf(xi - p.z) < eps);
        ny += (fabsf(yi - p.w) < eps);
    }

    // Cross-lane count reduce within group (totals <= 4096, no carry).
    int pk = (nx << 16) | ny;
#pragma unroll
    for (int m = 1; m < G; m <<= 1) pk += __shfl_xor(pk, m);

    if (l == 0)
        red[wv * 4 + g] = digammaf_dev((float)(pk >> 16))
                        + digammaf_dev((float)(pk & 0xffff));
    __syncthreads();

    if (threadIdx.x == 0) {
        float v = 0.f;
#pragma unroll
        for (int q = 0; q < ROWS_PER_BLOCK; ++q) v += red[q];
        ws[blockIdx.x] = v;                    // 1 partial per block
    }
}

__global__ void knnmi_final(const float* __restrict__ ws, float* __restrict__ out) {
    const int w    = threadIdx.x >> 6;    // wave = channel
    const int lane = threadIdx.x & 63;
    float sum = 0.f;
#pragma unroll
    for (int i = lane; i < BLOCKS_PER_CH; i += 64) sum += ws[w * BLOCKS_PER_CH + i];
#pragma unroll
    for (int m = 32; m; m >>= 1) sum += __shfl_xor(sum, m);
    if (lane == 0) {
        float mi = digammaf_dev((float)KNN) + digammaf_dev((float)HW)
                 - sum / (float)HW;
        out[w] = fmaxf(mi, 0.f);
    }
}

extern "C" void kernel_launch(void* const* d_in, const int* in_sizes, int n_in,
                              void* d_out, int out_size, void* d_ws, size_t ws_size,
                              hipStream_t stream) {
    const float* x = (const float*)d_in[0];
    const float* y = (const float*)d_in[1];
    float* out = (float*)d_out;
    float* ws  = (float*)d_ws;   // NBLOCKS floats, fully rewritten every call

    knnmi_rows<<<NBLOCKS, TPB, 0, stream>>>(x, y, ws);
    knnmi_final<<<1, NCH * 64, 0, stream>>>(ws, out);
}